// Round 5
// baseline (242.563 us; speedup 1.0000x reference)
//
#include <hip/hip_runtime.h>

#define N_NODES 50000
#define N_EDGES 800000
#define DIM 128
#define CHUNK 4096      // edges per chunk; 196*4096 >= 800000
#define GRID 196        // chunks == buckets == blocks for build passes
#define SEG_CAP 6144    // LDS csr segment cap (mean 4096, sigma 64)
#define GEMM_BLOCKS 391 // ceil(50000/128) -- 128 rows per block
#define GA 196          // gemm blocks co-gridded with sort_scatter
#define GB (GEMM_BLOCKS - GA)   // 195 co-gridded with csr_build

typedef __attribute__((ext_vector_type(8))) short bf16x8;   // 8 bf16 = 4 VGPRs
typedef __attribute__((ext_vector_type(4))) float f32x4;    // MFMA acc

// ---------------- bf16 pack/unpack (RNE) ----------------

__device__ inline unsigned rne_bf16(float f) {
    unsigned u = __float_as_uint(f);
    return (u + 0x7FFFu + ((u >> 16) & 1u)) >> 16;
}
__device__ inline unsigned pk_bf16(float a, float b) {
    return rne_bf16(a) | (rne_bf16(b) << 16);
}
__device__ inline float bf_lo(unsigned u) { return __uint_as_float(u << 16); }
__device__ inline float bf_hi(unsigned u) { return __uint_as_float(u & 0xFFFF0000u); }

// ---------------- deg zero (must precede atomic hist) ----------------

__global__ __launch_bounds__(256) void zero_deg(int* __restrict__ deg) {
    const int i = blockIdx.x * 256 + threadIdx.x;
    if (i < N_NODES) deg[i] = 0;
}

// ---------------- W -> MFMA fragment pre-pass (bf16 hi/lo split) -----------
// frag[tile=c*4+q][lane] = 8 bf16: B[k][col], k = q*32+(lane>>4)*8+j,
// col = c*16+(lane&15).

__device__ void fragw_build(const float* __restrict__ W, uint4* __restrict__ fh,
                            uint4* __restrict__ fl, int slot) {
    const int lane = slot & 63, tile = slot >> 6;     // tile 0..31
    const int c = tile >> 2, q = tile & 3;
    const int k0 = q * 32 + ((lane >> 4) << 3);
    const int col = c * 16 + (lane & 15);
    unsigned h[8], l[8];
#pragma unroll
    for (int j = 0; j < 8; ++j) {
        float w = W[(size_t)(k0 + j) * DIM + col];
        unsigned hb = rne_bf16(w);
        h[j] = hb;
        l[j] = rne_bf16(w - __uint_as_float(hb << 16));
    }
    uint4 uh, ul;
    uh.x = h[0] | (h[1] << 16); uh.y = h[2] | (h[3] << 16);
    uh.z = h[4] | (h[5] << 16); uh.w = h[6] | (h[7] << 16);
    ul.x = l[0] | (l[1] << 16); ul.y = l[2] | (l[3] << 16);
    ul.z = l[4] | (l[5] << 16); ul.w = l[6] | (l[7] << 16);
    fh[slot] = uh;
    fl[slot] = ul;
}

// ---------------- Pass A + fragW: co-gridded; also builds deg[] ------------

__global__ __launch_bounds__(256) void chunk_hist_fragw(const int* __restrict__ dst,
                                                        int* __restrict__ chist,
                                                        int* __restrict__ deg,
                                                        const float* __restrict__ W1,
                                                        const float* __restrict__ W2,
                                                        uint4* f1h, uint4* f1l,
                                                        uint4* f2h, uint4* f2l) {
    const int bid = blockIdx.x;
    if (bid < GRID) {
        __shared__ int hist[256];
        const int t = threadIdx.x;
        const int eb = bid * CHUNK;
        const int cnt = min(CHUNK, N_EDGES - eb);
        hist[t] = 0;
        __syncthreads();
        for (int i = t; i < cnt; i += 256) {
            int d = dst[eb + i];
            atomicAdd(&hist[d >> 8], 1);
            atomicAdd(&deg[d], 1);           // int atomics: deterministic
        }
        __syncthreads();
        chist[bid * 256 + t] = hist[t];
    } else {
        const int b2 = bid - GRID;                    // 0..15
        const int slot = (b2 & 7) * 256 + threadIdx.x; // 0..2047
        if (b2 < 8) fragw_build(W1, f1h, f1l, slot);
        else        fragw_build(W2, f2h, f2l, slot);
    }
}

// ---------------- MFMA GEMM body (layer 1): O = dinv*(X @ W), bf16 out -----
// Epilogue scales each row by rsqrt(deg+1) -> hp is PRE-SCALED (round-0 form).

__device__ void gemm_body(const float* __restrict__ X,
                          const uint4* __restrict__ fWh,
                          const uint4* __restrict__ fWl,
                          const int* __restrict__ deg,
                          uint2* __restrict__ O, int gb, char* smem) {
    const int t = threadIdx.x;

    {   // stage W fragments: hi at [0,32KB), lo at [32KB,64KB)
        uint4* s4 = (uint4*)smem;
        for (int i = t; i < 2048; i += 256) {
            s4[i] = fWh[i];
            s4[2048 + i] = fWl[i];
        }
    }
    __syncthreads();

    const int w = t >> 6, lane = t & 63;
    const int lrow = lane & 15, lgrp = lane >> 4;
    const int rbase = gb * 128;

    bf16x8 Ah[2][4], Al[2][4];
#pragma unroll
    for (int m = 0; m < 2; ++m) {
        const int r = rbase + w * 32 + m * 16 + lrow;
        const bool ok = (r < N_NODES);
        const float4* xp = (const float4*)(X + (size_t)r * DIM + lgrp * 8);
#pragma unroll
        for (int q = 0; q < 4; ++q) {
            float4 a0 = ok ? xp[q * 8]     : make_float4(0.f, 0.f, 0.f, 0.f);
            float4 a1 = ok ? xp[q * 8 + 1] : make_float4(0.f, 0.f, 0.f, 0.f);
            float f[8] = {a0.x, a0.y, a0.z, a0.w, a1.x, a1.y, a1.z, a1.w};
            bf16x8 hi, lo;
#pragma unroll
            for (int j = 0; j < 8; ++j) {
                unsigned hb = rne_bf16(f[j]);
                hi[j] = (short)hb;
                lo[j] = (short)rne_bf16(f[j] - __uint_as_float(hb << 16));
            }
            Ah[m][q] = hi;
            Al[m][q] = lo;
        }
    }

    f32x4 acc[2][8];
#pragma unroll
    for (int m = 0; m < 2; ++m)
#pragma unroll
        for (int c = 0; c < 8; ++c)
            acc[m][c] = (f32x4){0.f, 0.f, 0.f, 0.f};

    const bf16x8* Bh = (const bf16x8*)smem;
    const bf16x8* Bl = (const bf16x8*)(smem + 32768);
#pragma unroll
    for (int c = 0; c < 8; ++c) {
#pragma unroll
        for (int q = 0; q < 4; ++q) {
            bf16x8 bh = Bh[(c * 4 + q) * 64 + lane];
            bf16x8 bl = Bl[(c * 4 + q) * 64 + lane];
#pragma unroll
            for (int m = 0; m < 2; ++m) {
                acc[m][c] = __builtin_amdgcn_mfma_f32_16x16x32_bf16(Ah[m][q], bh, acc[m][c], 0, 0, 0);
                acc[m][c] = __builtin_amdgcn_mfma_f32_16x16x32_bf16(Al[m][q], bh, acc[m][c], 0, 0, 0);
                acc[m][c] = __builtin_amdgcn_mfma_f32_16x16x32_bf16(Ah[m][q], bl, acc[m][c], 0, 0, 0);
            }
        }
    }

    __syncthreads();
    float* Lf = (float*)smem;
#pragma unroll
    for (int m = 0; m < 2; ++m)
#pragma unroll
        for (int c = 0; c < 8; ++c)
#pragma unroll
            for (int rg = 0; rg < 4; ++rg)
                Lf[(w * 32 + m * 16 + lgrp * 4 + rg) * DIM + c * 16 + lrow] = acc[m][c][rg];
    __syncthreads();

    const float4* Lf4 = (const float4*)smem;
    for (int idx = t; idx < 4096; idx += 256) {
        const int row = idx >> 5, s = idx & 31;
        const int gr = rbase + row;
        if (gr < N_NODES) {
            float di = rsqrtf((float)deg[gr] + 1.0f);   // +1 self-loop
            float4 v = Lf4[idx];
            uint2 o;
            o.x = pk_bf16(v.x * di, v.y * di);
            o.y = pk_bf16(v.z * di, v.w * di);
            O[(size_t)gr * 32 + s] = o;
        }
    }
}

// ---------------- Pass B body: counting sort; offsets from chist -----------
// Block 0 additionally exports the bucket base scan (bbase_g) for pass C.

__device__ void sort_scatter_body(const int* __restrict__ src,
                                  const int* __restrict__ dst,
                                  const int* __restrict__ chist,
                                  unsigned* __restrict__ sorted,
                                  int* __restrict__ bbase_g,
                                  int bid, char* smem) {
    int* hist  = (int*)smem;
    int* sc    = hist + 256;
    int* lbase = sc + 256;
    int* lcur  = lbase + 256;
    int* gbase = lcur + 256;
    unsigned* sl = (unsigned*)(smem + 5 * 1024);   // CHUNK entries

    const int t = threadIdx.x;
    const int eb = bid * CHUNK;
    const int cnt = min(CHUNK, N_EDGES - eb);

    int sum = 0, myoff = 0;
    for (int c = 0; c < GRID; ++c) {
        int v = chist[c * 256 + t];
        if (c == bid) myoff = sum;
        sum += v;
    }
    hist[t] = chist[bid * 256 + t];
    sc[t] = sum;
    __syncthreads();
    for (int off = 1; off < 256; off <<= 1) {
        int u = (t >= off) ? sc[t - off] : 0;
        __syncthreads();
        sc[t] += u;
        __syncthreads();
    }
    gbase[t] = (sc[t] - sum) + myoff;
    if (bid == 0) bbase_g[t] = sc[t] - sum;   // exclusive scan of bucket totals
    __syncthreads();

    sc[t] = hist[t];
    __syncthreads();
    for (int off = 1; off < 256; off <<= 1) {
        int u = (t >= off) ? sc[t - off] : 0;
        __syncthreads();
        sc[t] += u;
        __syncthreads();
    }
    int ex = sc[t] - hist[t];
    lbase[t] = ex;
    lcur[t] = ex;
    __syncthreads();

    for (int i = t; i < cnt; i += 256) {
        int s = src[eb + i], d = dst[eb + i];
        int b = d >> 8;
        int p = atomicAdd(&lcur[b], 1);
        sl[p] = ((unsigned)b << 24) | ((unsigned)(d & 255) << 16) | (unsigned)s;
    }
    __syncthreads();
    for (int i = t; i < cnt; i += 256) {
        unsigned rec = sl[i];
        int b = rec >> 24;
        sorted[gbase[b] + (i - lbase[b])] = rec;
    }
}

// ---------------- Pass C body: per-bucket CSR finalize (bbase-driven) ------

__device__ void csr_build_body(const unsigned* __restrict__ sorted,
                               const int* __restrict__ bbase,
                               int* __restrict__ rowptr,
                               float* __restrict__ dinv,
                               int* __restrict__ csr,
                               int k, char* smem) {
    int* hist = (int*)smem;
    int* sc   = hist + 256;
    int* lcur = sc + 256;
    int* seg  = (int*)(smem + 3 * 1024);           // SEG_CAP entries

    const int t = threadIdx.x;
    const int base = bbase[k];
    const int cntk = ((k == 255) ? N_EDGES : bbase[k + 1]) - base;
    if (k == 0 && t == 0) rowptr[N_NODES] = N_EDGES;

    hist[t] = 0;
    __syncthreads();
    for (int i = t; i < cntk; i += 256)
        atomicAdd(&hist[(sorted[base + i] >> 16) & 255], 1);
    __syncthreads();

    const int node = (k << 8) + t;
    const int dv = hist[t];
    if (node < N_NODES) dinv[node] = rsqrtf((float)dv + 1.0f);   // +1 self-loop

    sc[t] = dv;
    __syncthreads();
    for (int off = 1; off < 256; off <<= 1) {
        int u = (t >= off) ? sc[t - off] : 0;
        __syncthreads();
        sc[t] += u;
        __syncthreads();
    }
    int ex = sc[t] - dv;
    if (node < N_NODES) rowptr[node] = base + ex;
    lcur[t] = ex;
    __syncthreads();

    if (cntk <= SEG_CAP) {
        for (int i = t; i < cntk; i += 256) {
            unsigned rec = sorted[base + i];
            int p = atomicAdd(&lcur[(rec >> 16) & 255], 1);
            seg[p] = (int)(rec & 0xFFFFu);
        }
        __syncthreads();
        for (int i = t; i < cntk; i += 256)
            csr[base + i] = seg[i];
    } else {
        for (int i = t; i < cntk; i += 256) {
            unsigned rec = sorted[base + i];
            int p = atomicAdd(&lcur[(rec >> 16) & 255], 1);
            csr[base + p] = (int)(rec & 0xFFFFu);
        }
    }
}

// ---------------- Fused dispatches: build blocks first, gemm backfills -----

__global__ __launch_bounds__(256, 2) void sort_gemm(const int* __restrict__ src,
                                                    const int* __restrict__ dst,
                                                    const int* __restrict__ chist,
                                                    unsigned* __restrict__ sorted,
                                                    int* __restrict__ bbase_g,
                                                    const float* __restrict__ X,
                                                    const uint4* __restrict__ fWh,
                                                    const uint4* __restrict__ fWl,
                                                    const int* __restrict__ deg,
                                                    uint2* __restrict__ O) {
    __shared__ __align__(16) char smem[65536];
    if (blockIdx.x < GRID)
        sort_scatter_body(src, dst, chist, sorted, bbase_g, blockIdx.x, smem);
    else
        gemm_body(X, fWh, fWl, deg, O, blockIdx.x - GRID, smem);
}

__global__ __launch_bounds__(256, 2) void csr_gemm(const unsigned* __restrict__ sorted,
                                                   const int* __restrict__ bbase,
                                                   int* __restrict__ rowptr,
                                                   float* __restrict__ dinv,
                                                   int* __restrict__ csr,
                                                   const float* __restrict__ X,
                                                   const uint4* __restrict__ fWh,
                                                   const uint4* __restrict__ fWl,
                                                   const int* __restrict__ deg,
                                                   uint2* __restrict__ O) {
    __shared__ __align__(16) char smem[65536];
    if (blockIdx.x < GRID)
        csr_build_body(sorted, bbase, rowptr, dinv, csr, blockIdx.x, smem);
    else
        gemm_body(X, fWh, fWl, deg, O, blockIdx.x - GRID + GA, smem);
}

// ---------------- per-node aggregation over PRE-SCALED message table -------
// H2 rows already hold dinv[s]*h[s]. Returns (sum*dn + bias [+relu]) on
// half==0 lanes. No per-edge dinv loads; self term is a plain row load.

__device__ inline float4 agg_node_ps(int node, const uint2* __restrict__ H2,
                                     const int* __restrict__ rowptr,
                                     const int* __restrict__ csr,
                                     const float* __restrict__ dinv,
                                     const float4* __restrict__ b4, int relu) {
    const int lane = threadIdx.x & 63;
    const int half = lane >> 5;
    const int col  = lane & 31;

    float4 acc = make_float4(0.f, 0.f, 0.f, 0.f);
    if (half == 0) {                      // self-loop term (pre-scaled row)
        uint2 v = H2[(size_t)node * 32 + col];
        acc.x = bf_lo(v.x); acc.y = bf_hi(v.x);
        acc.z = bf_lo(v.y); acc.w = bf_hi(v.y);
    }

    int j = rowptr[node];
    const int end = rowptr[node + 1];

#define ACCUM(v) do { \
        acc.x += bf_lo((v).x); acc.y += bf_hi((v).x); \
        acc.z += bf_lo((v).y); acc.w += bf_hi((v).y); } while (0)

    for (; j + 16 <= end; j += 16) {
        int s0 = csr[j +  0 + half], s1 = csr[j +  2 + half];
        int s2 = csr[j +  4 + half], s3 = csr[j +  6 + half];
        int s4 = csr[j +  8 + half], s5 = csr[j + 10 + half];
        int s6 = csr[j + 12 + half], s7 = csr[j + 14 + half];
        uint2 v0 = H2[(size_t)s0 * 32 + col];
        uint2 v1 = H2[(size_t)s1 * 32 + col];
        uint2 v2 = H2[(size_t)s2 * 32 + col];
        uint2 v3 = H2[(size_t)s3 * 32 + col];
        uint2 v4 = H2[(size_t)s4 * 32 + col];
        uint2 v5 = H2[(size_t)s5 * 32 + col];
        uint2 v6 = H2[(size_t)s6 * 32 + col];
        uint2 v7 = H2[(size_t)s7 * 32 + col];
        ACCUM(v0); ACCUM(v1); ACCUM(v2); ACCUM(v3);
        ACCUM(v4); ACCUM(v5); ACCUM(v6); ACCUM(v7);
    }
    if (j + 8 <= end) {
        int s0 = csr[j + half], s1 = csr[j + 2 + half];
        int s2 = csr[j + 4 + half], s3 = csr[j + 6 + half];
        uint2 v0 = H2[(size_t)s0 * 32 + col];
        uint2 v1 = H2[(size_t)s1 * 32 + col];
        uint2 v2 = H2[(size_t)s2 * 32 + col];
        uint2 v3 = H2[(size_t)s3 * 32 + col];
        ACCUM(v0); ACCUM(v1); ACCUM(v2); ACCUM(v3);
        j += 8;
    }
    if (j + 4 <= end) {
        int s0 = csr[j + half], s1 = csr[j + 2 + half];
        uint2 v0 = H2[(size_t)s0 * 32 + col];
        uint2 v1 = H2[(size_t)s1 * 32 + col];
        ACCUM(v0); ACCUM(v1);
        j += 4;
    }
    if (j + 2 <= end) {
        int s = csr[j + half];
        uint2 v = H2[(size_t)s * 32 + col];
        ACCUM(v);
        j += 2;
    }
    if (j < end && half == 0) {
        int s = csr[j];
        uint2 v = H2[(size_t)s * 32 + col];
        ACCUM(v);
    }
#undef ACCUM

    acc.x += __shfl_xor(acc.x, 32, 64);
    acc.y += __shfl_xor(acc.y, 32, 64);
    acc.z += __shfl_xor(acc.z, 32, 64);
    acc.w += __shfl_xor(acc.w, 32, 64);

    float4 o = make_float4(0.f, 0.f, 0.f, 0.f);
    if (half == 0) {
        const float dn = dinv[node];
        float4 bb = b4[col];
        o.x = acc.x * dn + bb.x;
        o.y = acc.y * dn + bb.y;
        o.z = acc.z * dn + bb.z;
        o.w = acc.w * dn + bb.w;
        if (relu) {
            o.x = fmaxf(o.x, 0.f); o.y = fmaxf(o.y, 0.f);
            o.z = fmaxf(o.z, 0.f); o.w = fmaxf(o.w, 0.f);
        }
    }
    return o;
}

// ---------------- layer-1 aggregate: h1' = dinv[n]*relu(h1[n]), bf16 hi/lo -
// Pre-scaling here makes gemm2's output rows pre-scaled too (linearity),
// so the final aggregate also needs no per-edge dinv.

__global__ __launch_bounds__(256) void aggregate_h1(const uint2* __restrict__ H2,
                                                    const int* __restrict__ rowptr,
                                                    const int* __restrict__ csr,
                                                    const float* __restrict__ dinv,
                                                    const float4* __restrict__ b4,
                                                    uint2* __restrict__ h1h,
                                                    uint2* __restrict__ h1l) {
    int node = blockIdx.x * 4 + (threadIdx.x >> 6);
    if (node >= N_NODES) return;
    float4 o = agg_node_ps(node, H2, rowptr, csr, dinv, b4, 1);
    const int lane = threadIdx.x & 63;
    if (lane < 32) {       // lane g holds cols 4g..4g+3
        const float dn = dinv[node];
        o.x *= dn; o.y *= dn; o.z *= dn; o.w *= dn;   // pre-scale for layer 2
        unsigned hx = rne_bf16(o.x), hy = rne_bf16(o.y);
        unsigned hz = rne_bf16(o.z), hw = rne_bf16(o.w);
        unsigned lx = rne_bf16(o.x - __uint_as_float(hx << 16));
        unsigned ly = rne_bf16(o.y - __uint_as_float(hy << 16));
        unsigned lz = rne_bf16(o.z - __uint_as_float(hz << 16));
        unsigned lw = rne_bf16(o.w - __uint_as_float(hw << 16));
        uint2 hv; hv.x = hx | (hy << 16); hv.y = hz | (hw << 16);
        uint2 lv; lv.x = lx | (ly << 16); lv.y = lz | (lw << 16);
        h1h[(size_t)node * 32 + lane] = hv;
        h1l[(size_t)node * 32 + lane] = lv;
    }
}

// ---------------- final aggregate (layer 2 output, fp32) -------------------

__global__ __launch_bounds__(256) void aggregate_out(const uint2* __restrict__ H2,
                                                     const int* __restrict__ rowptr,
                                                     const int* __restrict__ csr,
                                                     const float* __restrict__ dinv,
                                                     const float4* __restrict__ b4,
                                                     float4* __restrict__ out) {
    int node = blockIdx.x * 4 + (threadIdx.x >> 6);
    if (node >= N_NODES) return;
    float4 o = agg_node_ps(node, H2, rowptr, csr, dinv, b4, 0);
    const int lane = threadIdx.x & 63;
    if (lane < 32) out[(size_t)node * 32 + lane] = o;
}

// ---------------- layer-2 GEMM: A pre-split bf16 hi/lo, no split VALU ------
// Input h1' is pre-scaled -> output hp2' rows are pre-scaled (no epilogue
// scale needed here).

__global__ __launch_bounds__(256, 2) void gemm_xw2(const uint2* __restrict__ h1h,
                                                   const uint2* __restrict__ h1l,
                                                   const uint4* __restrict__ fWh,
                                                   const uint4* __restrict__ fWl,
                                                   uint2* __restrict__ O) {
    __shared__ __align__(16) char smem[65536];
    const int t = threadIdx.x;

    {   // stage W fragments: hi at [0,32KB), lo at [32KB,64KB)
        uint4* s4 = (uint4*)smem;
        for (int i = t; i < 2048; i += 256) {
            s4[i] = fWh[i];
            s4[2048 + i] = fWl[i];
        }
    }
    __syncthreads();

    const int w = t >> 6, lane = t & 63;
    const int lrow = lane & 15, lgrp = lane >> 4;
    const int rbase = blockIdx.x * 128;

    bf16x8 Ah[2][4], Al[2][4];
    const bf16x8 zz = (bf16x8){0,0,0,0,0,0,0,0};
#pragma unroll
    for (int m = 0; m < 2; ++m) {
        const int r = rbase + w * 32 + m * 16 + lrow;
        const bool ok = (r < N_NODES);
        // slot g covers cols 4g..4g+3; k0 = q*32+lgrp*8 -> slot q*8+lgrp*2
        const uint2* ph = h1h + (size_t)r * 32 + lgrp * 2;
        const uint2* pl = h1l + (size_t)r * 32 + lgrp * 2;
#pragma unroll
        for (int q = 0; q < 4; ++q) {
            Ah[m][q] = ok ? *(const bf16x8*)(ph + q * 8) : zz;
            Al[m][q] = ok ? *(const bf16x8*)(pl + q * 8) : zz;
        }
    }

    f32x4 acc[2][8];
#pragma unroll
    for (int m = 0; m < 2; ++m)
#pragma unroll
        for (int c = 0; c < 8; ++c)
            acc[m][c] = (f32x4){0.f, 0.f, 0.f, 0.f};

    const bf16x8* Bh = (const bf16x8*)smem;
    const bf16x8* Bl = (const bf16x8*)(smem + 32768);
#pragma unroll
    for (int c = 0; c < 8; ++c) {
#pragma unroll
        for (int q = 0; q < 4; ++q) {
            bf16x8 bh = Bh[(c * 4 + q) * 64 + lane];
            bf16x8 bl = Bl[(c * 4 + q) * 64 + lane];
#pragma unroll
            for (int m = 0; m < 2; ++m) {
                acc[m][c] = __builtin_amdgcn_mfma_f32_16x16x32_bf16(Ah[m][q], bh, acc[m][c], 0, 0, 0);
                acc[m][c] = __builtin_amdgcn_mfma_f32_16x16x32_bf16(Al[m][q], bh, acc[m][c], 0, 0, 0);
                acc[m][c] = __builtin_amdgcn_mfma_f32_16x16x32_bf16(Ah[m][q], bl, acc[m][c], 0, 0, 0);
            }
        }
    }

    __syncthreads();
    float* Lf = (float*)smem;
#pragma unroll
    for (int m = 0; m < 2; ++m)
#pragma unroll
        for (int c = 0; c < 8; ++c)
#pragma unroll
            for (int rg = 0; rg < 4; ++rg)
                Lf[(w * 32 + m * 16 + lgrp * 4 + rg) * DIM + c * 16 + lrow] = acc[m][c][rg];
    __syncthreads();

    const float4* Lf4 = (const float4*)smem;
    for (int idx = t; idx < 4096; idx += 256) {
        const int row = idx >> 5, s = idx & 31;
        const int gr = rbase + row;
        if (gr < N_NODES) {
            float4 v = Lf4[idx];
            uint2 o;
            o.x = pk_bf16(v.x, v.y);
            o.y = pk_bf16(v.z, v.w);
            O[(size_t)gr * 32 + s] = o;
        }
    }
}

// ---------------- launch ----------------

extern "C" void kernel_launch(void* const* d_in, const int* in_sizes, int n_in,
                              void* d_out, int out_size, void* d_ws, size_t ws_size,
                              hipStream_t stream) {
    const float* x  = (const float*)d_in[0];
    const int*   ei = (const int*)d_in[1];
    const float* W1 = (const float*)d_in[2];
    const float* b1 = (const float*)d_in[3];
    const float* W2 = (const float*)d_in[4];
    const float* b2 = (const float*)d_in[5];
    float* out = (float*)d_out;

    const int* src = ei;             // edge_index[0]
    const int* dst = ei + N_EDGES;   // edge_index[1]

    char* p = (char*)d_ws;
    int*      chist  = (int*)p;              p += GRID * 256 * 4;              // 200 KB
    float*    dinv   = (float*)p;            p += ((N_NODES * 4 + 1023) & ~1023);
    int*      rowptr = (int*)p;              p += (((N_NODES + 1) * 4 + 1023) & ~1023);
    unsigned* sorted = (unsigned*)p;         p += ((N_EDGES * 4 + 1023) & ~1023);
    int*      csr    = (int*)p;              p += ((N_EDGES * 4 + 1023) & ~1023);
    int*      bbase  = (int*)p;              p += 1024;                        // 256 ints
    int*      deg    = (int*)p;              p += ((N_NODES * 4 + 1023) & ~1023);
    uint4*    f1h    = (uint4*)p;            p += 32768;                       // W1 hi frags
    uint4*    f1l    = (uint4*)p;            p += 32768;                       // W1 lo frags
    uint4*    f2h    = (uint4*)p;            p += 32768;                       // W2 hi frags
    uint4*    f2l    = (uint4*)p;            p += 32768;                       // W2 lo frags
    uint2*    hp     = (uint2*)p;            p += (size_t)N_NODES * DIM * 2;   // pre-scaled layer1 lin (bf16)
    uint2*    h1h    = (uint2*)p;            p += (size_t)N_NODES * DIM * 2;   // h1' hi bf16
    uint2*    h1l    = (uint2*)p;            p += (size_t)N_NODES * DIM * 2;   // h1' lo bf16
    uint2*    hp2    = (uint2*)p;                                              // pre-scaled layer2 lin (bf16)

    const int aggBlocks = (N_NODES + 3) / 4;     // 12500

    // ---- deg zero, then pass A (+deg atomics) + W-fragment build ----
    zero_deg<<<(N_NODES + 255) / 256, 256, 0, stream>>>(deg);
    chunk_hist_fragw<<<GRID + 16, 256, 0, stream>>>(dst, chist, deg, W1, W2,
                                                    f1h, f1l, f2h, f2l);
    // ---- build + layer-1 MFMA GEMM (pre-scaled epilogue) co-gridded ----
    sort_gemm<<<GRID + GA, 256, 0, stream>>>(src, dst, chist, sorted, bbase,
                                             x, f1h, f1l, deg, hp);
    csr_gemm<<<GRID + GB, 256, 0, stream>>>(sorted, bbase, rowptr, dinv, csr,
                                            x, f1h, f1l, deg, hp);

    // ---- layer 1 aggregate (+b1, relu, pre-scale) -> h1' hi/lo ----
    aggregate_h1<<<aggBlocks, 256, 0, stream>>>(hp, rowptr, csr, dinv,
                                                (const float4*)b1, h1h, h1l);

    // ---- layer 2 MFMA GEMM (pre-split A) -> hp2' (pre-scaled) ----
    gemm_xw2<<<GEMM_BLOCKS, 256, 0, stream>>>(h1h, h1l, f2h, f2l, hp2);

    // ---- final aggregate -> out ----
    aggregate_out<<<aggBlocks, 256, 0, stream>>>(hp2, rowptr, csr, dinv,
                                                 (const float4*)b2, (float4*)out);
}

// Round 6
// 209.125 us; speedup vs baseline: 1.1599x; 1.1599x over previous
//
#include <hip/hip_runtime.h>

#define N_NODES 50000
#define N_EDGES 800000
#define DIM 128
#define CHUNK 4096      // edges per chunk; 196*4096 >= 800000
#define GRID 196        // chunks == buckets == blocks for build passes
#define SEG_CAP 6144    // LDS csr segment cap (mean 4096, sigma 64)
#define GEMM_BLOCKS 391 // ceil(50000/128) -- 128 rows per block
#define GA 316          // gemm blocks co-gridded with sort_scatter: 196+316=512 = 2/CU * 256 CU
#define GB (GEMM_BLOCKS - GA)   // 75 co-gridded with csr_build

typedef __attribute__((ext_vector_type(8))) short bf16x8;   // 8 bf16 = 4 VGPRs
typedef __attribute__((ext_vector_type(4))) float f32x4;    // MFMA acc

// ---------------- bf16 pack/unpack (RNE) ----------------

__device__ inline unsigned rne_bf16(float f) {
    unsigned u = __float_as_uint(f);
    return (u + 0x7FFFu + ((u >> 16) & 1u)) >> 16;
}
__device__ inline unsigned pk_bf16(float a, float b) {
    return rne_bf16(a) | (rne_bf16(b) << 16);
}
__device__ inline float bf_lo(unsigned u) { return __uint_as_float(u << 16); }
__device__ inline float bf_hi(unsigned u) { return __uint_as_float(u & 0xFFFF0000u); }

// ---------------- W -> MFMA fragment pre-pass (bf16 hi/lo split) -----------
// frag[tile=c*4+q][lane] = 8 bf16: B[k][col], k = q*32+(lane>>4)*8+j,
// col = c*16+(lane&15).

__device__ void fragw_build(const float* __restrict__ W, uint4* __restrict__ fh,
                            uint4* __restrict__ fl, int slot) {
    const int lane = slot & 63, tile = slot >> 6;     // tile 0..31
    const int c = tile >> 2, q = tile & 3;
    const int k0 = q * 32 + ((lane >> 4) << 3);
    const int col = c * 16 + (lane & 15);
    unsigned h[8], l[8];
#pragma unroll
    for (int j = 0; j < 8; ++j) {
        float w = W[(size_t)(k0 + j) * DIM + col];
        unsigned hb = rne_bf16(w);
        h[j] = hb;
        l[j] = rne_bf16(w - __uint_as_float(hb << 16));
    }
    uint4 uh, ul;
    uh.x = h[0] | (h[1] << 16); uh.y = h[2] | (h[3] << 16);
    uh.z = h[4] | (h[5] << 16); uh.w = h[6] | (h[7] << 16);
    ul.x = l[0] | (l[1] << 16); ul.y = l[2] | (l[3] << 16);
    ul.z = l[4] | (l[5] << 16); ul.w = l[6] | (l[7] << 16);
    fh[slot] = uh;
    fl[slot] = ul;
}

// ---------------- Pass A + fragW: co-gridded ----------------

__global__ __launch_bounds__(256) void chunk_hist_fragw(const int* __restrict__ dst,
                                                        int* __restrict__ chist,
                                                        const float* __restrict__ W1,
                                                        const float* __restrict__ W2,
                                                        uint4* f1h, uint4* f1l,
                                                        uint4* f2h, uint4* f2l) {
    const int bid = blockIdx.x;
    if (bid < GRID) {
        __shared__ int hist[256];
        const int t = threadIdx.x;
        const int eb = bid * CHUNK;
        const int cnt = min(CHUNK, N_EDGES - eb);
        hist[t] = 0;
        __syncthreads();
        for (int i = t; i < cnt; i += 256)
            atomicAdd(&hist[dst[eb + i] >> 8], 1);
        __syncthreads();
        chist[bid * 256 + t] = hist[t];
    } else {
        const int b2 = bid - GRID;                    // 0..15
        const int slot = (b2 & 7) * 256 + threadIdx.x; // 0..2047
        if (b2 < 8) fragw_build(W1, f1h, f1l, slot);
        else        fragw_build(W2, f2h, f2l, slot);
    }
}

// ---------------- MFMA GEMM body (layer 1): O = X[fp32] @ W, bf16 out ------

__device__ void gemm_body(const float* __restrict__ X,
                          const uint4* __restrict__ fWh,
                          const uint4* __restrict__ fWl,
                          uint2* __restrict__ O, int gb, char* smem) {
    const int t = threadIdx.x;

    {   // stage W fragments: hi at [0,32KB), lo at [32KB,64KB)
        uint4* s4 = (uint4*)smem;
        for (int i = t; i < 2048; i += 256) {
            s4[i] = fWh[i];
            s4[2048 + i] = fWl[i];
        }
    }
    __syncthreads();

    const int w = t >> 6, lane = t & 63;
    const int lrow = lane & 15, lgrp = lane >> 4;
    const int rbase = gb * 128;

    bf16x8 Ah[2][4], Al[2][4];
#pragma unroll
    for (int m = 0; m < 2; ++m) {
        const int r = rbase + w * 32 + m * 16 + lrow;
        const bool ok = (r < N_NODES);
        const float4* xp = (const float4*)(X + (size_t)r * DIM + lgrp * 8);
#pragma unroll
        for (int q = 0; q < 4; ++q) {
            float4 a0 = ok ? xp[q * 8]     : make_float4(0.f, 0.f, 0.f, 0.f);
            float4 a1 = ok ? xp[q * 8 + 1] : make_float4(0.f, 0.f, 0.f, 0.f);
            float f[8] = {a0.x, a0.y, a0.z, a0.w, a1.x, a1.y, a1.z, a1.w};
            bf16x8 hi, lo;
#pragma unroll
            for (int j = 0; j < 8; ++j) {
                unsigned hb = rne_bf16(f[j]);
                hi[j] = (short)hb;
                lo[j] = (short)rne_bf16(f[j] - __uint_as_float(hb << 16));
            }
            Ah[m][q] = hi;
            Al[m][q] = lo;
        }
    }

    f32x4 acc[2][8];
#pragma unroll
    for (int m = 0; m < 2; ++m)
#pragma unroll
        for (int c = 0; c < 8; ++c)
            acc[m][c] = (f32x4){0.f, 0.f, 0.f, 0.f};

    const bf16x8* Bh = (const bf16x8*)smem;
    const bf16x8* Bl = (const bf16x8*)(smem + 32768);
#pragma unroll
    for (int c = 0; c < 8; ++c) {
#pragma unroll
        for (int q = 0; q < 4; ++q) {
            bf16x8 bh = Bh[(c * 4 + q) * 64 + lane];
            bf16x8 bl = Bl[(c * 4 + q) * 64 + lane];
#pragma unroll
            for (int m = 0; m < 2; ++m) {
                acc[m][c] = __builtin_amdgcn_mfma_f32_16x16x32_bf16(Ah[m][q], bh, acc[m][c], 0, 0, 0);
                acc[m][c] = __builtin_amdgcn_mfma_f32_16x16x32_bf16(Al[m][q], bh, acc[m][c], 0, 0, 0);
                acc[m][c] = __builtin_amdgcn_mfma_f32_16x16x32_bf16(Ah[m][q], bl, acc[m][c], 0, 0, 0);
            }
        }
    }

    __syncthreads();
    float* Lf = (float*)smem;
#pragma unroll
    for (int m = 0; m < 2; ++m)
#pragma unroll
        for (int c = 0; c < 8; ++c)
#pragma unroll
            for (int rg = 0; rg < 4; ++rg)
                Lf[(w * 32 + m * 16 + lgrp * 4 + rg) * DIM + c * 16 + lrow] = acc[m][c][rg];
    __syncthreads();

    const float4* Lf4 = (const float4*)smem;
    for (int idx = t; idx < 4096; idx += 256) {
        const int row = idx >> 5, s = idx & 31;
        const int gr = rbase + row;
        if (gr < N_NODES) {
            float4 v = Lf4[idx];
            uint2 o;
            o.x = pk_bf16(v.x, v.y);
            o.y = pk_bf16(v.z, v.w);
            O[(size_t)gr * 32 + s] = o;
        }
    }
}

// ---------------- Pass B body: counting sort; offsets from chist -----------
// Block 0 additionally exports the bucket base scan (bbase_g) for pass C.

__device__ void sort_scatter_body(const int* __restrict__ src,
                                  const int* __restrict__ dst,
                                  const int* __restrict__ chist,
                                  unsigned* __restrict__ sorted,
                                  int* __restrict__ bbase_g,
                                  int bid, char* smem) {
    int* hist  = (int*)smem;
    int* sc    = hist + 256;
    int* lbase = sc + 256;
    int* lcur  = lbase + 256;
    int* gbase = lcur + 256;
    unsigned* sl = (unsigned*)(smem + 5 * 1024);   // CHUNK entries

    const int t = threadIdx.x;
    const int eb = bid * CHUNK;
    const int cnt = min(CHUNK, N_EDGES - eb);

    int sum = 0, myoff = 0;
    for (int c = 0; c < GRID; ++c) {
        int v = chist[c * 256 + t];
        if (c == bid) myoff = sum;
        sum += v;
    }
    hist[t] = chist[bid * 256 + t];
    sc[t] = sum;
    __syncthreads();
    for (int off = 1; off < 256; off <<= 1) {
        int u = (t >= off) ? sc[t - off] : 0;
        __syncthreads();
        sc[t] += u;
        __syncthreads();
    }
    gbase[t] = (sc[t] - sum) + myoff;
    if (bid == 0) bbase_g[t] = sc[t] - sum;   // exclusive scan of bucket totals
    __syncthreads();

    sc[t] = hist[t];
    __syncthreads();
    for (int off = 1; off < 256; off <<= 1) {
        int u = (t >= off) ? sc[t - off] : 0;
        __syncthreads();
        sc[t] += u;
        __syncthreads();
    }
    int ex = sc[t] - hist[t];
    lbase[t] = ex;
    lcur[t] = ex;
    __syncthreads();

    for (int i = t; i < cnt; i += 256) {
        int s = src[eb + i], d = dst[eb + i];
        int b = d >> 8;
        int p = atomicAdd(&lcur[b], 1);
        sl[p] = ((unsigned)b << 24) | ((unsigned)(d & 255) << 16) | (unsigned)s;
    }
    __syncthreads();
    for (int i = t; i < cnt; i += 256) {
        unsigned rec = sl[i];
        int b = rec >> 24;
        sorted[gbase[b] + (i - lbase[b])] = rec;
    }
}

// ---------------- Pass C body: per-bucket CSR finalize (bbase-driven) ------

__device__ void csr_build_body(const unsigned* __restrict__ sorted,
                               const int* __restrict__ bbase,
                               int* __restrict__ rowptr,
                               float* __restrict__ dinv,
                               int* __restrict__ csr,
                               int k, char* smem) {
    int* hist = (int*)smem;
    int* sc   = hist + 256;
    int* lcur = sc + 256;
    int* seg  = (int*)(smem + 3 * 1024);           // SEG_CAP entries

    const int t = threadIdx.x;
    const int base = bbase[k];
    const int cntk = ((k == 255) ? N_EDGES : bbase[k + 1]) - base;
    if (k == 0 && t == 0) rowptr[N_NODES] = N_EDGES;

    hist[t] = 0;
    __syncthreads();
    for (int i = t; i < cntk; i += 256)
        atomicAdd(&hist[(sorted[base + i] >> 16) & 255], 1);
    __syncthreads();

    const int node = (k << 8) + t;
    const int dv = hist[t];
    if (node < N_NODES) dinv[node] = rsqrtf((float)dv + 1.0f);   // +1 self-loop

    sc[t] = dv;
    __syncthreads();
    for (int off = 1; off < 256; off <<= 1) {
        int u = (t >= off) ? sc[t - off] : 0;
        __syncthreads();
        sc[t] += u;
        __syncthreads();
    }
    int ex = sc[t] - dv;
    if (node < N_NODES) rowptr[node] = base + ex;
    lcur[t] = ex;
    __syncthreads();

    if (cntk <= SEG_CAP) {
        for (int i = t; i < cntk; i += 256) {
            unsigned rec = sorted[base + i];
            int p = atomicAdd(&lcur[(rec >> 16) & 255], 1);
            seg[p] = (int)(rec & 0xFFFFu);
        }
        __syncthreads();
        for (int i = t; i < cntk; i += 256)
            csr[base + i] = seg[i];
    } else {
        for (int i = t; i < cntk; i += 256) {
            unsigned rec = sorted[base + i];
            int p = atomicAdd(&lcur[(rec >> 16) & 255], 1);
            csr[base + p] = (int)(rec & 0xFFFFu);
        }
    }
}

// ---------------- Fused dispatches: build blocks first, gemm backfills -----

__global__ __launch_bounds__(256, 2) void sort_gemm(const int* __restrict__ src,
                                                    const int* __restrict__ dst,
                                                    const int* __restrict__ chist,
                                                    unsigned* __restrict__ sorted,
                                                    int* __restrict__ bbase_g,
                                                    const float* __restrict__ X,
                                                    const uint4* __restrict__ fWh,
                                                    const uint4* __restrict__ fWl,
                                                    uint2* __restrict__ O) {
    __shared__ __align__(16) char smem[65536];
    if (blockIdx.x < GRID)
        sort_scatter_body(src, dst, chist, sorted, bbase_g, blockIdx.x, smem);
    else
        gemm_body(X, fWh, fWl, O, blockIdx.x - GRID, smem);
}

__global__ __launch_bounds__(256, 2) void csr_gemm(const unsigned* __restrict__ sorted,
                                                   const int* __restrict__ bbase,
                                                   int* __restrict__ rowptr,
                                                   float* __restrict__ dinv,
                                                   int* __restrict__ csr,
                                                   const float* __restrict__ X,
                                                   const uint4* __restrict__ fWh,
                                                   const uint4* __restrict__ fWl,
                                                   uint2* __restrict__ O) {
    __shared__ __align__(16) char smem[65536];
    if (blockIdx.x < GRID)
        csr_build_body(sorted, bbase, rowptr, dinv, csr, blockIdx.x, smem);
    else
        gemm_body(X, fWh, fWl, O, blockIdx.x - GRID + GA, smem);
}

// ---------------- per-node aggregation (shared by both layers) -------------
// Returns (acc*dn + bias [+relu]) on half==0 lanes; zeros elsewhere.

__device__ inline float4 agg_node(int node, const uint2* __restrict__ H2,
                                  const int* __restrict__ rowptr,
                                  const int* __restrict__ csr,
                                  const float* __restrict__ dinv,
                                  const float4* __restrict__ b4, int relu) {
    const int lane = threadIdx.x & 63;
    const int half = lane >> 5;
    const int col  = lane & 31;

    const float dn = dinv[node];
    float4 acc = make_float4(0.f, 0.f, 0.f, 0.f);
    if (half == 0) {                      // self-loop term: weight dinv[node]
        uint2 v = H2[(size_t)node * 32 + col];
        acc.x = dn * bf_lo(v.x); acc.y = dn * bf_hi(v.x);
        acc.z = dn * bf_lo(v.y); acc.w = dn * bf_hi(v.y);
    }

    int j = rowptr[node];
    const int end = rowptr[node + 1];

#define ACC(v, ds) do { \
        acc.x = fmaf((ds), bf_lo((v).x), acc.x); \
        acc.y = fmaf((ds), bf_hi((v).x), acc.y); \
        acc.z = fmaf((ds), bf_lo((v).y), acc.z); \
        acc.w = fmaf((ds), bf_hi((v).y), acc.w); } while (0)

    for (; j + 16 <= end; j += 16) {
        int s0 = csr[j +  0 + half], s1 = csr[j +  2 + half];
        int s2 = csr[j +  4 + half], s3 = csr[j +  6 + half];
        int s4 = csr[j +  8 + half], s5 = csr[j + 10 + half];
        int s6 = csr[j + 12 + half], s7 = csr[j + 14 + half];
        uint2 v0 = H2[(size_t)s0 * 32 + col]; float d0 = dinv[s0];
        uint2 v1 = H2[(size_t)s1 * 32 + col]; float d1 = dinv[s1];
        uint2 v2 = H2[(size_t)s2 * 32 + col]; float d2 = dinv[s2];
        uint2 v3 = H2[(size_t)s3 * 32 + col]; float d3 = dinv[s3];
        uint2 v4 = H2[(size_t)s4 * 32 + col]; float d4 = dinv[s4];
        uint2 v5 = H2[(size_t)s5 * 32 + col]; float d5 = dinv[s5];
        uint2 v6 = H2[(size_t)s6 * 32 + col]; float d6 = dinv[s6];
        uint2 v7 = H2[(size_t)s7 * 32 + col]; float d7 = dinv[s7];
        ACC(v0, d0); ACC(v1, d1); ACC(v2, d2); ACC(v3, d3);
        ACC(v4, d4); ACC(v5, d5); ACC(v6, d6); ACC(v7, d7);
    }
    if (j + 8 <= end) {
        int s0 = csr[j + half], s1 = csr[j + 2 + half];
        int s2 = csr[j + 4 + half], s3 = csr[j + 6 + half];
        uint2 v0 = H2[(size_t)s0 * 32 + col]; float d0 = dinv[s0];
        uint2 v1 = H2[(size_t)s1 * 32 + col]; float d1 = dinv[s1];
        uint2 v2 = H2[(size_t)s2 * 32 + col]; float d2 = dinv[s2];
        uint2 v3 = H2[(size_t)s3 * 32 + col]; float d3 = dinv[s3];
        ACC(v0, d0); ACC(v1, d1); ACC(v2, d2); ACC(v3, d3);
        j += 8;
    }
    if (j + 4 <= end) {
        int s0 = csr[j + half], s1 = csr[j + 2 + half];
        uint2 v0 = H2[(size_t)s0 * 32 + col]; float d0 = dinv[s0];
        uint2 v1 = H2[(size_t)s1 * 32 + col]; float d1 = dinv[s1];
        ACC(v0, d0); ACC(v1, d1);
        j += 4;
    }
    if (j + 2 <= end) {
        int s = csr[j + half];
        uint2 v = H2[(size_t)s * 32 + col]; float d0 = dinv[s];
        ACC(v, d0);
        j += 2;
    }
    if (j < end && half == 0) {
        int s = csr[j];
        uint2 v = H2[(size_t)s * 32 + col]; float d0 = dinv[s];
        ACC(v, d0);
    }
#undef ACC

    acc.x += __shfl_xor(acc.x, 32, 64);
    acc.y += __shfl_xor(acc.y, 32, 64);
    acc.z += __shfl_xor(acc.z, 32, 64);
    acc.w += __shfl_xor(acc.w, 32, 64);

    float4 o = make_float4(0.f, 0.f, 0.f, 0.f);
    if (half == 0) {
        float4 bb = b4[col];
        o.x = acc.x * dn + bb.x;
        o.y = acc.y * dn + bb.y;
        o.z = acc.z * dn + bb.z;
        o.w = acc.w * dn + bb.w;
        if (relu) {
            o.x = fmaxf(o.x, 0.f); o.y = fmaxf(o.y, 0.f);
            o.z = fmaxf(o.z, 0.f); o.w = fmaxf(o.w, 0.f);
        }
    }
    return o;
}

// ---------------- layer-1 aggregate: writes h1 as bf16 hi/lo tables --------

__global__ __launch_bounds__(256) void aggregate_h1(const uint2* __restrict__ H2,
                                                    const int* __restrict__ rowptr,
                                                    const int* __restrict__ csr,
                                                    const float* __restrict__ dinv,
                                                    const float4* __restrict__ b4,
                                                    uint2* __restrict__ h1h,
                                                    uint2* __restrict__ h1l) {
    int node = blockIdx.x * 4 + (threadIdx.x >> 6);
    if (node >= N_NODES) return;
    float4 o = agg_node(node, H2, rowptr, csr, dinv, b4, 1);
    const int lane = threadIdx.x & 63;
    if (lane < 32) {       // lane g holds cols 4g..4g+3
        unsigned hx = rne_bf16(o.x), hy = rne_bf16(o.y);
        unsigned hz = rne_bf16(o.z), hw = rne_bf16(o.w);
        unsigned lx = rne_bf16(o.x - __uint_as_float(hx << 16));
        unsigned ly = rne_bf16(o.y - __uint_as_float(hy << 16));
        unsigned lz = rne_bf16(o.z - __uint_as_float(hz << 16));
        unsigned lw = rne_bf16(o.w - __uint_as_float(hw << 16));
        uint2 hv; hv.x = hx | (hy << 16); hv.y = hz | (hw << 16);
        uint2 lv; lv.x = lx | (ly << 16); lv.y = lz | (lw << 16);
        h1h[(size_t)node * 32 + lane] = hv;
        h1l[(size_t)node * 32 + lane] = lv;
    }
}

// ---------------- final aggregate (layer 2 output, fp32) -------------------

__global__ __launch_bounds__(256) void aggregate_out(const uint2* __restrict__ H2,
                                                     const int* __restrict__ rowptr,
                                                     const int* __restrict__ csr,
                                                     const float* __restrict__ dinv,
                                                     const float4* __restrict__ b4,
                                                     float4* __restrict__ out) {
    int node = blockIdx.x * 4 + (threadIdx.x >> 6);
    if (node >= N_NODES) return;
    float4 o = agg_node(node, H2, rowptr, csr, dinv, b4, 0);
    const int lane = threadIdx.x & 63;
    if (lane < 32) out[(size_t)node * 32 + lane] = o;
}

// ---------------- layer-2 GEMM: A pre-split bf16 hi/lo, no split VALU ------

__global__ __launch_bounds__(256, 2) void gemm_xw2(const uint2* __restrict__ h1h,
                                                   const uint2* __restrict__ h1l,
                                                   const uint4* __restrict__ fWh,
                                                   const uint4* __restrict__ fWl,
                                                   uint2* __restrict__ O) {
    __shared__ __align__(16) char smem[65536];
    const int t = threadIdx.x;

    {   // stage W fragments: hi at [0,32KB), lo at [32KB,64KB)
        uint4* s4 = (uint4*)smem;
        for (int i = t; i < 2048; i += 256) {
            s4[i] = fWh[i];
            s4[2048 + i] = fWl[i];
        }
    }
    __syncthreads();

    const int w = t >> 6, lane = t & 63;
    const int lrow = lane & 15, lgrp = lane >> 4;
    const int rbase = blockIdx.x * 128;

    bf16x8 Ah[2][4], Al[2][4];
    const bf16x8 zz = (bf16x8){0,0,0,0,0,0,0,0};
#pragma unroll
    for (int m = 0; m < 2; ++m) {
        const int r = rbase + w * 32 + m * 16 + lrow;
        const bool ok = (r < N_NODES);
        // slot g covers cols 4g..4g+3; k0 = q*32+lgrp*8 -> slot q*8+lgrp*2
        const uint2* ph = h1h + (size_t)r * 32 + lgrp * 2;
        const uint2* pl = h1l + (size_t)r * 32 + lgrp * 2;
#pragma unroll
        for (int q = 0; q < 4; ++q) {
            Ah[m][q] = ok ? *(const bf16x8*)(ph + q * 8) : zz;
            Al[m][q] = ok ? *(const bf16x8*)(pl + q * 8) : zz;
        }
    }

    f32x4 acc[2][8];
#pragma unroll
    for (int m = 0; m < 2; ++m)
#pragma unroll
        for (int c = 0; c < 8; ++c)
            acc[m][c] = (f32x4){0.f, 0.f, 0.f, 0.f};

    const bf16x8* Bh = (const bf16x8*)smem;
    const bf16x8* Bl = (const bf16x8*)(smem + 32768);
#pragma unroll
    for (int c = 0; c < 8; ++c) {
#pragma unroll
        for (int q = 0; q < 4; ++q) {
            bf16x8 bh = Bh[(c * 4 + q) * 64 + lane];
            bf16x8 bl = Bl[(c * 4 + q) * 64 + lane];
#pragma unroll
            for (int m = 0; m < 2; ++m) {
                acc[m][c] = __builtin_amdgcn_mfma_f32_16x16x32_bf16(Ah[m][q], bh, acc[m][c], 0, 0, 0);
                acc[m][c] = __builtin_amdgcn_mfma_f32_16x16x32_bf16(Al[m][q], bh, acc[m][c], 0, 0, 0);
                acc[m][c] = __builtin_amdgcn_mfma_f32_16x16x32_bf16(Ah[m][q], bl, acc[m][c], 0, 0, 0);
            }
        }
    }

    __syncthreads();
    float* Lf = (float*)smem;
#pragma unroll
    for (int m = 0; m < 2; ++m)
#pragma unroll
        for (int c = 0; c < 8; ++c)
#pragma unroll
            for (int rg = 0; rg < 4; ++rg)
                Lf[(w * 32 + m * 16 + lgrp * 4 + rg) * DIM + c * 16 + lrow] = acc[m][c][rg];
    __syncthreads();

    const float4* Lf4 = (const float4*)smem;
    for (int idx = t; idx < 4096; idx += 256) {
        const int row = idx >> 5, s = idx & 31;
        const int gr = rbase + row;
        if (gr < N_NODES) {
            float4 v = Lf4[idx];
            uint2 o;
            o.x = pk_bf16(v.x, v.y);
            o.y = pk_bf16(v.z, v.w);
            O[(size_t)gr * 32 + s] = o;
        }
    }
}

// ---------------- launch ----------------

extern "C" void kernel_launch(void* const* d_in, const int* in_sizes, int n_in,
                              void* d_out, int out_size, void* d_ws, size_t ws_size,
                              hipStream_t stream) {
    const float* x  = (const float*)d_in[0];
    const int*   ei = (const int*)d_in[1];
    const float* W1 = (const float*)d_in[2];
    const float* b1 = (const float*)d_in[3];
    const float* W2 = (const float*)d_in[4];
    const float* b2 = (const float*)d_in[5];
    float* out = (float*)d_out;

    const int* src = ei;             // edge_index[0]
    const int* dst = ei + N_EDGES;   // edge_index[1]

    char* p = (char*)d_ws;
    int*      chist  = (int*)p;              p += GRID * 256 * 4;              // 200 KB
    float*    dinv   = (float*)p;            p += ((N_NODES * 4 + 1023) & ~1023);
    int*      rowptr = (int*)p;              p += (((N_NODES + 1) * 4 + 1023) & ~1023);
    unsigned* sorted = (unsigned*)p;         p += ((N_EDGES * 4 + 1023) & ~1023);
    int*      csr    = (int*)p;              p += ((N_EDGES * 4 + 1023) & ~1023);
    int*      bbase  = (int*)p;              p += 1024;                        // 256 ints
    uint4*    f1h    = (uint4*)p;            p += 32768;                       // W1 hi frags
    uint4*    f1l    = (uint4*)p;            p += 32768;                       // W1 lo frags
    uint4*    f2h    = (uint4*)p;            p += 32768;                       // W2 hi frags
    uint4*    f2l    = (uint4*)p;            p += 32768;                       // W2 lo frags
    uint2*    hp     = (uint2*)p;            p += (size_t)N_NODES * DIM * 2;   // bf16 layer1 lin table
    uint2*    h1h    = (uint2*)p;            p += (size_t)N_NODES * DIM * 2;   // h1 hi bf16
    uint2*    h1l    = (uint2*)p;            p += (size_t)N_NODES * DIM * 2;   // h1 lo bf16
    uint2*    hp2    = (uint2*)p;                                              // bf16 layer2 lin table

    const int aggBlocks = (N_NODES + 3) / 4;     // 12500

    // ---- pass A + W-fragment build (co-gridded) ----
    chunk_hist_fragw<<<GRID + 16, 256, 0, stream>>>(dst, chist, W1, W2,
                                                    f1h, f1l, f2h, f2l);
    // ---- build + layer-1 MFMA GEMM co-gridded ----
    // SG = 196 sort + 316 gemm = 512 blocks = 2/CU * 256 CUs (full chip);
    // CG = 196 csr + 75 gemm = 271 blocks.
    sort_gemm<<<GRID + GA, 256, 0, stream>>>(src, dst, chist, sorted, bbase,
                                             x, f1h, f1l, hp);
    csr_gemm<<<GRID + GB, 256, 0, stream>>>(sorted, bbase, rowptr, dinv, csr,
                                            x, f1h, f1l, hp);

    // ---- layer 1 aggregate (+b1, relu) -> h1 hi/lo bf16 tables ----
    aggregate_h1<<<aggBlocks, 256, 0, stream>>>(hp, rowptr, csr, dinv,
                                                (const float4*)b1, h1h, h1l);

    // ---- layer 2 MFMA GEMM (pre-split A) -> hp2 ----
    gemm_xw2<<<GEMM_BLOCKS, 256, 0, stream>>>(h1h, h1l, f2h, f2l, hp2);

    // ---- final aggregate -> out ----
    aggregate_out<<<aggBlocks, 256, 0, stream>>>(hp2, rowptr, csr, dinv,
                                                 (const float4*)b2, (float4*)out);
}